// Round 10
// baseline (324.201 us; speedup 1.0000x reference)
//
#include <hip/hip_runtime.h>
#include <hip/hip_fp16.h>

#define N_NODES 100000
#define N_EDGES 1600000
#define N_GRAPHS 2048
#define NFEAT 78
#define DIM 32
#define NLAYERS 5
#define OUTD 128
#define BN_EPS 1e-5f
#define NPB 32                       // nodes per layer-block
#define NBUK 391                     // coarse buckets (256 nodes each)
#define BNODES 256                   // nodes per bucket
#define STRIDE 4608                  // slab per bucket (mean 4092, +8 sigma)
#define EPB 4096                     // edges per bfill block
#define NBLK ((N_EDGES + EPB - 1) / EPB)      // 391
#define NSLOTS2 ((N_NODES / NPB + 63) / 64)   // 49 partial-stats slots

// fp16 helpers: unsigned holds 2 halfs
__device__ __forceinline__ float2 up2(unsigned u) {
    __half2 h = *reinterpret_cast<__half2*>(&u);
    return __half22float2(h);
}
__device__ __forceinline__ unsigned pk2(float a, float b) {
    __half2 h = __floats2half2_rn(a, b);
    return *reinterpret_cast<unsigned*>(&h);
}

// ---- prep: blocks [0,NBLK) do block-aggregated bucket fill;
//      blocks [NBLK, NBLK+3125) do gemm1 (x @ W1_0 -> fp16). Independent. ----
__global__ __launch_bounds__(256) void prep_kernel(
    const int* __restrict__ ei, int* __restrict__ bcnt, int* __restrict__ bdata,
    const float* __restrict__ x, const float* __restrict__ W1_0,
    unsigned short* __restrict__ y)
{
    __shared__ int cur[NBUK];
    __shared__ int gbl[NBUK];
    __shared__ float Wl[NFEAT * DIM];   // 9.75 KB
    int tid = threadIdx.x;

    if (blockIdx.x < NBLK) {
        // ---------------- bucket fill ----------------
        int base = blockIdx.x * EPB;
        for (int i = tid; i < NBUK; i += 256) cur[i] = 0;
        __syncthreads();

        int ew[16], eb[16];
        const int4* s4 = (const int4*)ei;
        const int4* d4 = (const int4*)(ei + N_EDGES);
#pragma unroll
        for (int c = 0; c < 4; ++c) {
            int eidx = base + c * 1024 + tid * 4;
            if (eidx < N_EDGES) {
                int4 sv = s4[eidx >> 2];
                int4 dv = d4[eidx >> 2];
                ew[c*4+0] = sv.x | ((dv.x & 255) << 17); eb[c*4+0] = dv.x >> 8;
                ew[c*4+1] = sv.y | ((dv.y & 255) << 17); eb[c*4+1] = dv.y >> 8;
                ew[c*4+2] = sv.z | ((dv.z & 255) << 17); eb[c*4+2] = dv.z >> 8;
                ew[c*4+3] = sv.w | ((dv.w & 255) << 17); eb[c*4+3] = dv.w >> 8;
            } else {
                eb[c*4+0] = eb[c*4+1] = eb[c*4+2] = eb[c*4+3] = -1;
                ew[c*4+0] = ew[c*4+1] = ew[c*4+2] = ew[c*4+3] = 0;
            }
        }
        int slot[16];
#pragma unroll
        for (int k = 0; k < 16; ++k)
            slot[k] = (eb[k] >= 0) ? atomicAdd(&cur[eb[k]], 1) : 0;
        __syncthreads();
        for (int b = tid; b < NBUK; b += 256) {
            int c = cur[b];
            gbl[b] = (c > 0) ? atomicAdd(&bcnt[b], c) : 0;
        }
        __syncthreads();
#pragma unroll
        for (int k = 0; k < 16; ++k) {
            int b = eb[k];
            if (b >= 0) {
                int pos = gbl[b] + slot[k];
                if (pos < STRIDE) bdata[b * STRIDE + pos] = ew[k];
            }
        }
    } else {
        // ---------------- gemm1: y0 = x @ W1_0 -> fp16 ----------------
        for (int i = tid; i < NFEAT * DIM; i += 256) Wl[i] = W1_0[i];
        __syncthreads();
        int t = (blockIdx.x - NBLK) * 256 + tid;
        int row = t >> 3;
        int c0 = (t & 7) * 4;
        float a0 = 0.f, a1 = 0.f, a2 = 0.f, a3 = 0.f;
        const float* hr = x + (long)row * NFEAT;
        for (int k = 0; k < NFEAT; ++k) {
            float xv = hr[k];
            a0 = fmaf(xv, Wl[k * DIM + c0 + 0], a0);
            a1 = fmaf(xv, Wl[k * DIM + c0 + 1], a1);
            a2 = fmaf(xv, Wl[k * DIM + c0 + 2], a2);
            a3 = fmaf(xv, Wl[k * DIM + c0 + 3], a3);
        }
        ((uint2*)y)[(long)row * 8 + (t & 7)] = make_uint2(pk2(a0, a1), pk2(a2, a3));
    }
}

// ---- bscan: exclusive scan of 391 bucket totals -> bbase[0..391] ----
__global__ __launch_bounds__(512) void bscan_kernel(
    const int* __restrict__ bcnt, int* __restrict__ bbase)
{
    __shared__ int sd[512];
    int t = threadIdx.x;
    int v = (t < NBUK) ? min(bcnt[t], STRIDE) : 0;
    sd[t] = v; __syncthreads();
    for (int off = 1; off < 512; off <<= 1) {
        int a = (t >= off) ? sd[t - off] : 0;
        __syncthreads();
        sd[t] += a;
        __syncthreads();
    }
    if (t < NBUK) bbase[t + 1] = sd[t];
    if (t == 0) bbase[0] = 0;
}

// ---- cfill2: per-bucket LDS counting sort -> flat CSR (edge_src, offs) ----
__global__ __launch_bounds__(256) void cfill2_kernel(
    const int* __restrict__ bcnt, const int* __restrict__ bbase,
    const int* __restrict__ bdata, int* __restrict__ edge_src,
    int* __restrict__ offs)
{
    __shared__ int sorted[STRIDE];          // 18.4 KB
    __shared__ int cnt[BNODES], off[BNODES], cur[BNODES];
    int b = blockIdx.x, tid = threadIdx.x;
    int n = min(bcnt[b], STRIDE);
    int gb = bbase[b];
    const int* slab = bdata + (long)b * STRIDE;

    if (tid < BNODES) cnt[tid] = 0;
    __syncthreads();
    for (int i = tid; i < n; i += 256)
        atomicAdd(&cnt[slab[i] >> 17], 1);
    __syncthreads();
    int t = tid;
    if (t < BNODES) off[t] = cnt[t];
    __syncthreads();
    for (int o = 1; o < BNODES; o <<= 1) {
        int a = (t >= o && t < BNODES) ? off[t - o] : 0;
        __syncthreads();
        if (t < BNODES) off[t] += a;
        __syncthreads();
    }
    if (t < BNODES) {
        int excl = off[t] - cnt[t];
        off[t] = excl;
        cur[t] = excl;
        int node = b * BNODES + t;
        if (node <= N_NODES) offs[node] = gb + excl;
    }
    __syncthreads();
    for (int i = tid; i < n; i += 256) {
        int w = slab[i];
        int pos = atomicAdd(&cur[w >> 17], 1);
        sorted[pos] = w & 0x1FFFF;
    }
    __syncthreads();
    for (int i = tid; i < n; i += 256)
        edge_src[gb + i] = sorted[i];
}

// ---- fused layer (flat CSR, barrier-free register pipeline):
//      fp16 gather -> shfl-matmul W1' -> relu -> shfl-matmul W2 -> relu
//      -> fp16 zout + BN partials.  Block = 32 nodes, 8 lanes/node. ----
template<bool MM>
__global__ __launch_bounds__(256) void layer_kernel(
    const int* __restrict__ offs, const int* __restrict__ edge_src,
    const unsigned short* __restrict__ zin, const float* __restrict__ W1p,
    const float* __restrict__ cvec, const float* __restrict__ b1v,
    const float* __restrict__ W2, const float* __restrict__ b2v,
    unsigned short* __restrict__ zout, float* __restrict__ partial)
{
    __shared__ float W1l[DIM * DIM];
    __shared__ float W2l[DIM * DIM];
    __shared__ float b1l[DIM], b2l[DIM], cl[DIM];
    __shared__ float psum[DIM], psq[DIM];

    int tid = threadIdx.x;
    if (MM) for (int i = tid; i < DIM * DIM; i += 256) W1l[i] = W1p[i];
    for (int i = tid; i < DIM * DIM; i += 256) W2l[i] = W2[i];
    if (tid < DIM) {
        b1l[tid] = b1v[tid]; b2l[tid] = b2v[tid];
        cl[tid] = MM ? cvec[tid] : 0.f;
        psum[tid] = 0.f; psq[tid] = 0.f;
    }
    __syncthreads();   // the only pre-compute barrier

    int ln = tid >> 3, p = tid & 7;
    int c0 = p * 4;
    int gbase = (tid & 63) & ~7;    // lane of p=0 in this node's 8-lane group
    long node = (long)blockIdx.x * NPB + ln;
    int beg = offs[node], end = offs[node + 1];
    int deg = end - beg;
    const uint2* zb = (const uint2*)zin;

    // phase 1: gather (self + in-neighbors), unroll x8
    uint2 sv = zb[node * 8 + p];
    float2 t01 = up2(sv.x), t23 = up2(sv.y);
    float a0 = t01.x, a1 = t01.y, a2 = t23.x, a3 = t23.y;
    int e = beg;
    for (; e + 8 <= end; e += 8) {
        uint2 v0 = zb[(long)edge_src[e + 0] * 8 + p];
        uint2 v1 = zb[(long)edge_src[e + 1] * 8 + p];
        uint2 v2 = zb[(long)edge_src[e + 2] * 8 + p];
        uint2 v3 = zb[(long)edge_src[e + 3] * 8 + p];
        uint2 v4 = zb[(long)edge_src[e + 4] * 8 + p];
        uint2 v5 = zb[(long)edge_src[e + 5] * 8 + p];
        uint2 v6 = zb[(long)edge_src[e + 6] * 8 + p];
        uint2 v7 = zb[(long)edge_src[e + 7] * 8 + p];
        float2 f;
        f = up2(v0.x); a0 += f.x; a1 += f.y;  f = up2(v0.y); a2 += f.x; a3 += f.y;
        f = up2(v1.x); a0 += f.x; a1 += f.y;  f = up2(v1.y); a2 += f.x; a3 += f.y;
        f = up2(v2.x); a0 += f.x; a1 += f.y;  f = up2(v2.y); a2 += f.x; a3 += f.y;
        f = up2(v3.x); a0 += f.x; a1 += f.y;  f = up2(v3.y); a2 += f.x; a3 += f.y;
        f = up2(v4.x); a0 += f.x; a1 += f.y;  f = up2(v4.y); a2 += f.x; a3 += f.y;
        f = up2(v5.x); a0 += f.x; a1 += f.y;  f = up2(v5.y); a2 += f.x; a3 += f.y;
        f = up2(v6.x); a0 += f.x; a1 += f.y;  f = up2(v6.y); a2 += f.x; a3 += f.y;
        f = up2(v7.x); a0 += f.x; a1 += f.y;  f = up2(v7.y); a2 += f.x; a3 += f.y;
    }
    for (; e < end; ++e) {
        uint2 v = zb[(long)edge_src[e] * 8 + p];
        float2 f;
        f = up2(v.x); a0 += f.x; a1 += f.y;
        f = up2(v.y); a2 += f.x; a3 += f.y;
    }

    // phase 2: s = zsum@W1' + (deg+1)*c + b1 (or zsum + b1), relu.
    // channel k of zsum lives at lane gbase+(k>>2), component k&3.
    float r0, r1, r2, r3;
    if (MM) {
        float s0 = 0.f, s1 = 0.f, s2 = 0.f, s3 = 0.f;
#pragma unroll
        for (int k = 0; k < DIM; ++k) {
            float comp = ((k & 3) == 0) ? a0 : ((k & 3) == 1) ? a1
                       : ((k & 3) == 2) ? a2 : a3;
            float zk = __shfl(comp, gbase + (k >> 2), 64);
            s0 = fmaf(zk, W1l[k * DIM + c0 + 0], s0);
            s1 = fmaf(zk, W1l[k * DIM + c0 + 1], s1);
            s2 = fmaf(zk, W1l[k * DIM + c0 + 2], s2);
            s3 = fmaf(zk, W1l[k * DIM + c0 + 3], s3);
        }
        float dp1 = (float)(deg + 1);
        r0 = fmaxf(fmaf(dp1, cl[c0 + 0], s0) + b1l[c0 + 0], 0.f);
        r1 = fmaxf(fmaf(dp1, cl[c0 + 1], s1) + b1l[c0 + 1], 0.f);
        r2 = fmaxf(fmaf(dp1, cl[c0 + 2], s2) + b1l[c0 + 2], 0.f);
        r3 = fmaxf(fmaf(dp1, cl[c0 + 3], s3) + b1l[c0 + 3], 0.f);
    } else {
        r0 = fmaxf(a0 + b1l[c0 + 0], 0.f);
        r1 = fmaxf(a1 + b1l[c0 + 1], 0.f);
        r2 = fmaxf(a2 + b1l[c0 + 2], 0.f);
        r3 = fmaxf(a3 + b1l[c0 + 3], 0.f);
    }

    // phase 3: z = relu(r@W2 + b2), same shuffle pattern
    float z0 = b2l[c0 + 0], z1 = b2l[c0 + 1], z2 = b2l[c0 + 2], z3 = b2l[c0 + 3];
#pragma unroll
    for (int k = 0; k < DIM; ++k) {
        float comp = ((k & 3) == 0) ? r0 : ((k & 3) == 1) ? r1
                   : ((k & 3) == 2) ? r2 : r3;
        float rk = __shfl(comp, gbase + (k >> 2), 64);
        z0 = fmaf(rk, W2l[k * DIM + c0 + 0], z0);
        z1 = fmaf(rk, W2l[k * DIM + c0 + 1], z1);
        z2 = fmaf(rk, W2l[k * DIM + c0 + 2], z2);
        z3 = fmaf(rk, W2l[k * DIM + c0 + 3], z3);
    }
    z0 = fmaxf(z0, 0.f); z1 = fmaxf(z1, 0.f);
    z2 = fmaxf(z2, 0.f); z3 = fmaxf(z3, 0.f);
    ((uint2*)zout)[node * 8 + p] = make_uint2(pk2(z0, z1), pk2(z2, z3));

    // BN partial stats
    float zv[4] = { z0, z1, z2, z3 };
    float sq[4] = { z0*z0, z1*z1, z2*z2, z3*z3 };
#pragma unroll
    for (int off = 8; off < 64; off <<= 1) {
#pragma unroll
        for (int j = 0; j < 4; ++j) {
            zv[j] += __shfl_xor(zv[j], off, 64);
            sq[j] += __shfl_xor(sq[j], off, 64);
        }
    }
    if ((tid & 63) < 8) {
#pragma unroll
        for (int j = 0; j < 4; ++j) {
            atomicAdd(&psum[c0 + j], zv[j]);
            atomicAdd(&psq[c0 + j], sq[j]);
        }
    }
    __syncthreads();
    if (tid < 2 * DIM) {
        float v = (tid < DIM) ? psum[tid] : psq[tid - DIM];
        atomicAdd(&partial[(long)(blockIdx.x >> 6) * 2 * DIM + tid], v);
    }
}

// ------ finalize: stats -> scale/shift; fold next layer's W1' and c ------
__global__ __launch_bounds__(256) void finalize_kernel(
    const float* __restrict__ partial,
    const float* __restrict__ gamma, const float* __restrict__ beta,
    float* __restrict__ ss, const float* W1next,
    float* __restrict__ W1p, float* __restrict__ cvec)
{
    __shared__ float red[256];
    __shared__ float sscl[DIM], sshl[DIM];
    int t = threadIdx.x;
    int c = t & 63;
    int chunk = t >> 6;
    float a = 0.f;
    for (int p = chunk; p < NSLOTS2; p += 4) a += partial[(long)p * 64 + c];
    red[t] = a; __syncthreads();
    if (t < 64) red[t] = red[t] + red[t + 64] + red[t + 128] + red[t + 192];
    __syncthreads();
    if (t < DIM) {
        const float invN = 1.0f / (float)N_NODES;
        float S = red[t], Q = red[t + DIM];
        float mu = S * invN;
        float var = Q * invN - mu * mu;
        float scale = gamma[t] * rsqrtf(var + BN_EPS);
        float shift = beta[t] - mu * scale;
        ss[t] = scale; ss[DIM + t] = shift;
        sscl[t] = scale; sshl[t] = shift;
    }
    __syncthreads();
    if (W1next) {
        for (int i = t; i < DIM * DIM; i += 256)
            W1p[i] = sscl[i >> 5] * W1next[i];
        if (t < DIM) {
            float cv = 0.f;
            for (int k = 0; k < DIM; ++k)
                cv += sshl[k] * W1next[k * DIM + t];
            cvec[t] = cv;
        }
    }
}

// ------- pool: pooled[g] += affine(zfp16[node]); sorted-batch LDS dedup -------
__global__ __launch_bounds__(256) void pool_kernel(
    const unsigned short* __restrict__ z, const int* __restrict__ batch,
    const float* __restrict__ ss, float* __restrict__ pooled)
{
    __shared__ float acc[32][32];
    __shared__ int slot[32];
    __shared__ int segg[32];
    __shared__ int nsegS;
    __shared__ float scl[DIM], shl[DIM];
    int tid = threadIdx.x;
    for (int i = tid; i < 1024; i += 256) ((float*)acc)[i] = 0.f;
    if (tid < DIM) { scl[tid] = ss[tid]; shl[tid] = ss[DIM + tid]; }
    int nodeBase = blockIdx.x * 32;
    if (tid < 32) {
        int nd = nodeBase + tid;
        int gv = batch[nd];
        int flag = (tid == 0) ? 1 : (gv != batch[nd - 1]);
        unsigned long long m = __ballot(flag);
        int s = __popcll(m & ((2ull << tid) - 1ull)) - 1;
        slot[tid] = s;
        if (flag) segg[s] = gv;
        if (tid == 0) nsegS = __popcll(m);
    }
    __syncthreads();

    int ln = tid >> 3;
    int p = tid & 7;
    long node = nodeBase + ln;
    uint2 u = ((const uint2*)z)[node * 8 + p];
    int c = p * 4;
    float2 f01 = up2(u.x), f23 = up2(u.y);
    float vx = fmaf(f01.x, scl[c+0], shl[c+0]);
    float vy = fmaf(f01.y, scl[c+1], shl[c+1]);
    float vz = fmaf(f23.x, scl[c+2], shl[c+2]);
    float vw = fmaf(f23.y, scl[c+3], shl[c+3]);
    int s = slot[ln];
    atomicAdd(&acc[s][c+0], vx);
    atomicAdd(&acc[s][c+1], vy);
    atomicAdd(&acc[s][c+2], vz);
    atomicAdd(&acc[s][c+3], vw);
    __syncthreads();

    int total = nsegS * 32;
    for (int i = tid; i < total; i += 256) {
        int r = i >> 5, dd = i & 31;
        float val = acc[r][dd];
        if (val != 0.f) atomicAdd(&pooled[(long)segg[r] * DIM + dd], val);
    }
}

// ---------------- final FC + ReLU ----------------
__global__ __launch_bounds__(256) void fc_kernel(
    const float* __restrict__ pooled, const float* __restrict__ Wfc,
    const float* __restrict__ bfc, float* __restrict__ out)
{
    __shared__ float Wl[DIM * OUTD];   // 16 KB
    for (int i = threadIdx.x; i < DIM * OUTD; i += 256) Wl[i] = Wfc[i];
    __syncthreads();
    int t = blockIdx.x * 256 + threadIdx.x;
    if (t >= N_GRAPHS * OUTD) return;
    int g = t >> 7;
    int o = t & (OUTD - 1);
    float acc = bfc[o];
    const float* pr = pooled + (long)g * DIM;
#pragma unroll
    for (int k = 0; k < DIM; ++k) acc += pr[k] * Wl[k * OUTD + o];
    out[t] = fmaxf(acc, 0.f);
}

extern "C" void kernel_launch(void* const* d_in, const int* in_sizes, int n_in,
                              void* d_out, int out_size, void* d_ws, size_t ws_size,
                              hipStream_t stream) {
    const float* x      = (const float*)d_in[0];
    const int*   ei     = (const int*)  d_in[1];
    const int*   batch  = (const int*)  d_in[2];
    const float* W1_0   = (const float*)d_in[3];
    const float* W1_rest= (const float*)d_in[4];
    const float* b1     = (const float*)d_in[5];
    const float* W2     = (const float*)d_in[6];
    const float* b2     = (const float*)d_in[7];
    const float* gamma  = (const float*)d_in[8];
    const float* beta   = (const float*)d_in[9];
    const float* Wfc    = (const float*)d_in[10];
    const float* bfc    = (const float*)d_in[11];
    float* out = (float*)d_out;

    int* wsi = (int*)d_ws;
    const size_t nf = (size_t)N_NODES * DIM;                   // 3.2M elems
    const size_t BD = (size_t)NBUK * STRIDE;                   // 1,801,728 ints
    // no overlays: bfill2 and gemm1 run concurrently in prep_kernel
    int*   bdata  = wsi;
    unsigned short* zfpA = (unsigned short*)(wsi + BD);        // 6.4 MB
    unsigned short* zfpB = zfpA + nf;                          // 6.4 MB
    int*   edge_src = (int*)(zfpB + nf);                       // 1.6M ints
    int*   offs   = edge_src + N_EDGES;                        // 100,001
    int*   bcnt   = offs + (N_NODES + 1);                      // 391
    int*   bbase  = bcnt + NBUK;                               // 392
    float* pooled = (float*)(bbase + NBUK + 1);                // 65,536
    float* partial= pooled + (size_t)N_GRAPHS * DIM;           // 5*49*64
    float* ss     = partial + (size_t)NLAYERS * NSLOTS2 * 2 * DIM;
    float* W1p    = ss + NLAYERS * 2 * DIM;
    float* cvec   = W1p + NLAYERS * DIM * DIM;

    hipMemsetAsync(pooled, 0,
        ((size_t)N_GRAPHS * DIM + (size_t)NLAYERS * NSLOTS2 * 2 * DIM) *
        sizeof(float), stream);
    hipMemsetAsync(bcnt, 0, (size_t)NBUK * sizeof(int), stream);

    const int grpBlocks = (N_NODES * 8) / 256;                 // 3125

    // prep: bucket fill (391 blocks) || gemm1 (3125 blocks)
    prep_kernel<<<NBLK + grpBlocks, 256, 0, stream>>>(
        ei, bcnt, bdata, x, W1_0, zfpA);
    bscan_kernel<<<1, 512, 0, stream>>>(bcnt, bbase);
    cfill2_kernel<<<NBUK, 256, 0, stream>>>(bcnt, bbase, bdata, edge_src, offs);

    // layer 0: gather y0, no matmul fold
    layer_kernel<false><<<N_NODES / NPB, 256, 0, stream>>>(
        offs, edge_src, zfpA, nullptr, nullptr,
        b1, W2, b2, zfpB, partial);
    finalize_kernel<<<1, 256, 0, stream>>>(
        partial, gamma, beta, ss,
        W1_rest, W1p + DIM * DIM, cvec + DIM);

    // layers 1..4: fused affine+W1 fold
    const unsigned short* zi = zfpB;
    unsigned short* zo = zfpA;
    for (int i = 1; i < NLAYERS; ++i) {
        layer_kernel<true><<<N_NODES / NPB, 256, 0, stream>>>(
            offs, edge_src, zi,
            W1p + (size_t)i * DIM * DIM, cvec + (size_t)i * DIM,
            b1 + i * DIM, W2 + (size_t)i * DIM * DIM, b2 + i * DIM,
            zo, partial + (size_t)i * NSLOTS2 * 2 * DIM);
        const float* W1next = (i + 1 < NLAYERS) ? (W1_rest + (size_t)i * DIM * DIM)
                                                : nullptr;
        finalize_kernel<<<1, 256, 0, stream>>>(
            partial + (size_t)i * NSLOTS2 * 2 * DIM,
            gamma + i * DIM, beta + i * DIM, ss + i * 2 * DIM,
            W1next, W1p + (size_t)(i + 1) * DIM * DIM,
            cvec + (size_t)(i + 1) * DIM);
        const unsigned short* tmp = zi; zi = zo; zo = (unsigned short*)tmp;
    }

    // zi points at the final layer's output
    pool_kernel<<<N_NODES / 32, 256, 0, stream>>>(
        zi, batch, ss + (NLAYERS - 1) * 2 * DIM, pooled);
    fc_kernel<<<(N_GRAPHS * OUTD) / 256, 256, 0, stream>>>(pooled, Wfc, bfc, out);
}

// Round 11
// 301.371 us; speedup vs baseline: 1.0758x; 1.0758x over previous
//
#include <hip/hip_runtime.h>
#include <hip/hip_fp16.h>

#define N_NODES 100000
#define N_EDGES 1600000
#define N_GRAPHS 2048
#define NFEAT 78
#define DIM 32
#define NLAYERS 5
#define OUTD 128
#define BN_EPS 1e-5f
#define NPB 32                       // nodes per layer-block
#define NBUK 391                     // coarse buckets (256 nodes each)
#define BNODES 256                   // nodes per bucket
#define STRIDE 4608                  // slab per bucket (mean 4092, +8 sigma)
#define EPB 4096                     // edges per bfill block
#define NBLK ((N_EDGES + EPB - 1) / EPB)      // 391
#define NSLOTS2 ((N_NODES / NPB + 63) / 64)   // 49 partial-stats slots

// fp16 helpers: unsigned holds 2 halfs
__device__ __forceinline__ float2 up2(unsigned u) {
    __half2 h = *reinterpret_cast<__half2*>(&u);
    return __half22float2(h);
}
__device__ __forceinline__ unsigned pk2(float a, float b) {
    __half2 h = __floats2half2_rn(a, b);
    return *reinterpret_cast<unsigned*>(&h);
}

// ---- prep: blocks [0,NBLK) do block-aggregated bucket fill;
//      blocks [NBLK, NBLK+3125) do gemm1 (x @ W1_0 -> fp16). Independent. ----
__global__ __launch_bounds__(256) void prep_kernel(
    const int* __restrict__ ei, int* __restrict__ bcnt, int* __restrict__ bdata,
    const float* __restrict__ x, const float* __restrict__ W1_0,
    unsigned short* __restrict__ y)
{
    __shared__ int cur[NBUK];
    __shared__ int gbl[NBUK];
    __shared__ float Wl[NFEAT * DIM];   // 9.75 KB
    int tid = threadIdx.x;

    if (blockIdx.x < NBLK) {
        // ---------------- bucket fill ----------------
        int base = blockIdx.x * EPB;
        for (int i = tid; i < NBUK; i += 256) cur[i] = 0;
        __syncthreads();

        int ew[16], eb[16];
        const int4* s4 = (const int4*)ei;
        const int4* d4 = (const int4*)(ei + N_EDGES);
#pragma unroll
        for (int c = 0; c < 4; ++c) {
            int eidx = base + c * 1024 + tid * 4;
            if (eidx < N_EDGES) {
                int4 sv = s4[eidx >> 2];
                int4 dv = d4[eidx >> 2];
                ew[c*4+0] = sv.x | ((dv.x & 255) << 17); eb[c*4+0] = dv.x >> 8;
                ew[c*4+1] = sv.y | ((dv.y & 255) << 17); eb[c*4+1] = dv.y >> 8;
                ew[c*4+2] = sv.z | ((dv.z & 255) << 17); eb[c*4+2] = dv.z >> 8;
                ew[c*4+3] = sv.w | ((dv.w & 255) << 17); eb[c*4+3] = dv.w >> 8;
            } else {
                eb[c*4+0] = eb[c*4+1] = eb[c*4+2] = eb[c*4+3] = -1;
                ew[c*4+0] = ew[c*4+1] = ew[c*4+2] = ew[c*4+3] = 0;
            }
        }
        int slot[16];
#pragma unroll
        for (int k = 0; k < 16; ++k)
            slot[k] = (eb[k] >= 0) ? atomicAdd(&cur[eb[k]], 1) : 0;
        __syncthreads();
        for (int b = tid; b < NBUK; b += 256) {
            int c = cur[b];
            gbl[b] = (c > 0) ? atomicAdd(&bcnt[b], c) : 0;
        }
        __syncthreads();
#pragma unroll
        for (int k = 0; k < 16; ++k) {
            int b = eb[k];
            if (b >= 0) {
                int pos = gbl[b] + slot[k];
                if (pos < STRIDE) bdata[b * STRIDE + pos] = ew[k];
            }
        }
    } else {
        // ---------------- gemm1: y0 = x @ W1_0 -> fp16 ----------------
        for (int i = tid; i < NFEAT * DIM; i += 256) Wl[i] = W1_0[i];
        __syncthreads();
        int t = (blockIdx.x - NBLK) * 256 + tid;
        int row = t >> 3;
        int c0 = (t & 7) * 4;
        float a0 = 0.f, a1 = 0.f, a2 = 0.f, a3 = 0.f;
        const float* hr = x + (long)row * NFEAT;
        for (int k = 0; k < NFEAT; ++k) {
            float xv = hr[k];
            a0 = fmaf(xv, Wl[k * DIM + c0 + 0], a0);
            a1 = fmaf(xv, Wl[k * DIM + c0 + 1], a1);
            a2 = fmaf(xv, Wl[k * DIM + c0 + 2], a2);
            a3 = fmaf(xv, Wl[k * DIM + c0 + 3], a3);
        }
        ((uint2*)y)[(long)row * 8 + (t & 7)] = make_uint2(pk2(a0, a1), pk2(a2, a3));
    }
}

// ---- bscan: exclusive scan of 391 bucket totals -> bbase[0..391] ----
__global__ __launch_bounds__(512) void bscan_kernel(
    const int* __restrict__ bcnt, int* __restrict__ bbase)
{
    __shared__ int sd[512];
    int t = threadIdx.x;
    int v = (t < NBUK) ? min(bcnt[t], STRIDE) : 0;
    sd[t] = v; __syncthreads();
    for (int off = 1; off < 512; off <<= 1) {
        int a = (t >= off) ? sd[t - off] : 0;
        __syncthreads();
        sd[t] += a;
        __syncthreads();
    }
    if (t < NBUK) bbase[t + 1] = sd[t];
    if (t == 0) bbase[0] = 0;
}

// ---- cfill2: per-bucket LDS counting sort -> flat CSR (edge_src, offs) ----
__global__ __launch_bounds__(256) void cfill2_kernel(
    const int* __restrict__ bcnt, const int* __restrict__ bbase,
    const int* __restrict__ bdata, int* __restrict__ edge_src,
    int* __restrict__ offs)
{
    __shared__ int sorted[STRIDE];          // 18.4 KB
    __shared__ int cnt[BNODES], off[BNODES], cur[BNODES];
    int b = blockIdx.x, tid = threadIdx.x;
    int n = min(bcnt[b], STRIDE);
    int gb = bbase[b];
    const int* slab = bdata + (long)b * STRIDE;

    if (tid < BNODES) cnt[tid] = 0;
    __syncthreads();
    for (int i = tid; i < n; i += 256)
        atomicAdd(&cnt[slab[i] >> 17], 1);
    __syncthreads();
    int t = tid;
    if (t < BNODES) off[t] = cnt[t];
    __syncthreads();
    for (int o = 1; o < BNODES; o <<= 1) {
        int a = (t >= o && t < BNODES) ? off[t - o] : 0;
        __syncthreads();
        if (t < BNODES) off[t] += a;
        __syncthreads();
    }
    if (t < BNODES) {
        int excl = off[t] - cnt[t];
        off[t] = excl;
        cur[t] = excl;
        int node = b * BNODES + t;
        if (node <= N_NODES) offs[node] = gb + excl;
    }
    __syncthreads();
    for (int i = tid; i < n; i += 256) {
        int w = slab[i];
        int pos = atomicAdd(&cur[w >> 17], 1);
        sorted[pos] = w & 0x1FFFF;
    }
    __syncthreads();
    for (int i = tid; i < n; i += 256)
        edge_src[gb + i] = sorted[i];
}

// ---- fused layer (flat CSR): fp16 gather -> [@W1'+(deg+1)c+b1] -> relu
//      -> @W2+b2 -> relu -> fp16 zout + BN partials.  Block = 32 nodes,
//      8 lanes/node; zs/srow rows are WAVE-private -> no inter-phase
//      barriers (same-wave DS ops are ordered). ----
template<bool MM>
__global__ __launch_bounds__(256) void layer_kernel(
    const int* __restrict__ offs, const int* __restrict__ edge_src,
    const unsigned short* __restrict__ zin, const float* __restrict__ W1p,
    const float* __restrict__ cvec, const float* __restrict__ b1v,
    const float* __restrict__ W2, const float* __restrict__ b2v,
    unsigned short* __restrict__ zout, float* __restrict__ partial)
{
    __shared__ float W1l[DIM * DIM];
    __shared__ float W2l[DIM * DIM];
    __shared__ float zs[NPB][36];
    __shared__ float srow[NPB][36];
    __shared__ float b1l[DIM], b2l[DIM], cl[DIM];
    __shared__ float psum[DIM], psq[DIM];

    int tid = threadIdx.x;
    if (MM) for (int i = tid; i < DIM * DIM; i += 256) W1l[i] = W1p[i];
    for (int i = tid; i < DIM * DIM; i += 256) W2l[i] = W2[i];
    if (tid < DIM) {
        b1l[tid] = b1v[tid]; b2l[tid] = b2v[tid];
        cl[tid] = MM ? cvec[tid] : 0.f;
        psum[tid] = 0.f; psq[tid] = 0.f;
    }
    __syncthreads();   // weights visible to all waves

    int ln = tid >> 3, p = tid & 7;
    int c0 = p * 4;
    long node = (long)blockIdx.x * NPB + ln;
    int beg = offs[node], end = offs[node + 1];
    int deg = end - beg;
    const uint2* zb = (const uint2*)zin;

    // phase 1: gather (self + in-neighbors), unroll x8
    uint2 sv = zb[node * 8 + p];
    float2 t01 = up2(sv.x), t23 = up2(sv.y);
    float a0 = t01.x, a1 = t01.y, a2 = t23.x, a3 = t23.y;
    int e = beg;
    for (; e + 8 <= end; e += 8) {
        uint2 v0 = zb[(long)edge_src[e + 0] * 8 + p];
        uint2 v1 = zb[(long)edge_src[e + 1] * 8 + p];
        uint2 v2 = zb[(long)edge_src[e + 2] * 8 + p];
        uint2 v3 = zb[(long)edge_src[e + 3] * 8 + p];
        uint2 v4 = zb[(long)edge_src[e + 4] * 8 + p];
        uint2 v5 = zb[(long)edge_src[e + 5] * 8 + p];
        uint2 v6 = zb[(long)edge_src[e + 6] * 8 + p];
        uint2 v7 = zb[(long)edge_src[e + 7] * 8 + p];
        float2 f;
        f = up2(v0.x); a0 += f.x; a1 += f.y;  f = up2(v0.y); a2 += f.x; a3 += f.y;
        f = up2(v1.x); a0 += f.x; a1 += f.y;  f = up2(v1.y); a2 += f.x; a3 += f.y;
        f = up2(v2.x); a0 += f.x; a1 += f.y;  f = up2(v2.y); a2 += f.x; a3 += f.y;
        f = up2(v3.x); a0 += f.x; a1 += f.y;  f = up2(v3.y); a2 += f.x; a3 += f.y;
        f = up2(v4.x); a0 += f.x; a1 += f.y;  f = up2(v4.y); a2 += f.x; a3 += f.y;
        f = up2(v5.x); a0 += f.x; a1 += f.y;  f = up2(v5.y); a2 += f.x; a3 += f.y;
        f = up2(v6.x); a0 += f.x; a1 += f.y;  f = up2(v6.y); a2 += f.x; a3 += f.y;
        f = up2(v7.x); a0 += f.x; a1 += f.y;  f = up2(v7.y); a2 += f.x; a3 += f.y;
    }
    for (; e < end; ++e) {
        uint2 v = zb[(long)edge_src[e] * 8 + p];
        float2 f;
        f = up2(v.x); a0 += f.x; a1 += f.y;
        f = up2(v.y); a2 += f.x; a3 += f.y;
    }
    *(float4*)&zs[ln][c0] = make_float4(a0, a1, a2, a3);
    // no barrier: zs row ln is only read by this wave (same-wave DS order)

    // phase 2: s = zsum@W1' + (deg+1)*c + b1  (or zsum + b1), relu
    float sv4[4];
    if (MM) {
        sv4[0] = sv4[1] = sv4[2] = sv4[3] = 0.f;
#pragma unroll
        for (int k = 0; k < DIM; ++k) {
            float zk = zs[ln][k];
            sv4[0] = fmaf(zk, W1l[k * DIM + c0 + 0], sv4[0]);
            sv4[1] = fmaf(zk, W1l[k * DIM + c0 + 1], sv4[1]);
            sv4[2] = fmaf(zk, W1l[k * DIM + c0 + 2], sv4[2]);
            sv4[3] = fmaf(zk, W1l[k * DIM + c0 + 3], sv4[3]);
        }
        float dp1 = (float)(deg + 1);
#pragma unroll
        for (int j = 0; j < 4; ++j)
            sv4[j] = fmaf(dp1, cl[c0 + j], sv4[j]) + b1l[c0 + j];
    } else {
        sv4[0] = a0 + b1l[c0 + 0]; sv4[1] = a1 + b1l[c0 + 1];
        sv4[2] = a2 + b1l[c0 + 2]; sv4[3] = a3 + b1l[c0 + 3];
    }
    float4 srw = make_float4(fmaxf(sv4[0], 0.f), fmaxf(sv4[1], 0.f),
                             fmaxf(sv4[2], 0.f), fmaxf(sv4[3], 0.f));
    *(float4*)&srow[ln][c0] = srw;
    // no barrier: srow row ln is wave-private

    // phase 3: z = relu(srow@W2 + b2), fp16 write + stats
    float zv[4] = { b2l[c0 + 0], b2l[c0 + 1], b2l[c0 + 2], b2l[c0 + 3] };
#pragma unroll
    for (int k = 0; k < DIM; ++k) {
        float sk = srow[ln][k];
        zv[0] = fmaf(sk, W2l[k * DIM + c0 + 0], zv[0]);
        zv[1] = fmaf(sk, W2l[k * DIM + c0 + 1], zv[1]);
        zv[2] = fmaf(sk, W2l[k * DIM + c0 + 2], zv[2]);
        zv[3] = fmaf(sk, W2l[k * DIM + c0 + 3], zv[3]);
    }
#pragma unroll
    for (int j = 0; j < 4; ++j) zv[j] = fmaxf(zv[j], 0.f);
    ((uint2*)zout)[node * 8 + p] = make_uint2(pk2(zv[0], zv[1]), pk2(zv[2], zv[3]));

    float sq[4];
#pragma unroll
    for (int j = 0; j < 4; ++j) sq[j] = zv[j] * zv[j];
#pragma unroll
    for (int off = 8; off < 64; off <<= 1) {
#pragma unroll
        for (int j = 0; j < 4; ++j) {
            zv[j] += __shfl_xor(zv[j], off, 64);
            sq[j] += __shfl_xor(sq[j], off, 64);
        }
    }
    if ((tid & 63) < 8) {
#pragma unroll
        for (int j = 0; j < 4; ++j) {
            atomicAdd(&psum[c0 + j], zv[j]);
            atomicAdd(&psq[c0 + j], sq[j]);
        }
    }
    __syncthreads();   // stats are block-shared
    if (tid < 2 * DIM) {
        float v = (tid < DIM) ? psum[tid] : psq[tid - DIM];
        atomicAdd(&partial[(long)(blockIdx.x >> 6) * 2 * DIM + tid], v);
    }
}

// ------ finalize: stats -> scale/shift; fold next layer's W1' and c ------
__global__ __launch_bounds__(256) void finalize_kernel(
    const float* __restrict__ partial,
    const float* __restrict__ gamma, const float* __restrict__ beta,
    float* __restrict__ ss, const float* W1next,
    float* __restrict__ W1p, float* __restrict__ cvec)
{
    __shared__ float red[256];
    __shared__ float sscl[DIM], sshl[DIM];
    int t = threadIdx.x;
    int c = t & 63;
    int chunk = t >> 6;
    float a = 0.f;
    for (int p = chunk; p < NSLOTS2; p += 4) a += partial[(long)p * 64 + c];
    red[t] = a; __syncthreads();
    if (t < 64) red[t] = red[t] + red[t + 64] + red[t + 128] + red[t + 192];
    __syncthreads();
    if (t < DIM) {
        const float invN = 1.0f / (float)N_NODES;
        float S = red[t], Q = red[t + DIM];
        float mu = S * invN;
        float var = Q * invN - mu * mu;
        float scale = gamma[t] * rsqrtf(var + BN_EPS);
        float shift = beta[t] - mu * scale;
        ss[t] = scale; ss[DIM + t] = shift;
        sscl[t] = scale; sshl[t] = shift;
    }
    __syncthreads();
    if (W1next) {
        for (int i = t; i < DIM * DIM; i += 256)
            W1p[i] = sscl[i >> 5] * W1next[i];
        if (t < DIM) {
            float cv = 0.f;
            for (int k = 0; k < DIM; ++k)
                cv += sshl[k] * W1next[k * DIM + t];
            cvec[t] = cv;
        }
    }
}

// ------- pool: pooled[g] += affine(zfp16[node]); sorted-batch LDS dedup -------
__global__ __launch_bounds__(256) void pool_kernel(
    const unsigned short* __restrict__ z, const int* __restrict__ batch,
    const float* __restrict__ ss, float* __restrict__ pooled)
{
    __shared__ float acc[32][32];
    __shared__ int slot[32];
    __shared__ int segg[32];
    __shared__ int nsegS;
    __shared__ float scl[DIM], shl[DIM];
    int tid = threadIdx.x;
    for (int i = tid; i < 1024; i += 256) ((float*)acc)[i] = 0.f;
    if (tid < DIM) { scl[tid] = ss[tid]; shl[tid] = ss[DIM + tid]; }
    int nodeBase = blockIdx.x * 32;
    if (tid < 32) {
        int nd = nodeBase + tid;
        int gv = batch[nd];
        int flag = (tid == 0) ? 1 : (gv != batch[nd - 1]);
        unsigned long long m = __ballot(flag);
        int s = __popcll(m & ((2ull << tid) - 1ull)) - 1;
        slot[tid] = s;
        if (flag) segg[s] = gv;
        if (tid == 0) nsegS = __popcll(m);
    }
    __syncthreads();

    int ln = tid >> 3;
    int p = tid & 7;
    long node = nodeBase + ln;
    uint2 u = ((const uint2*)z)[node * 8 + p];
    int c = p * 4;
    float2 f01 = up2(u.x), f23 = up2(u.y);
    float vx = fmaf(f01.x, scl[c+0], shl[c+0]);
    float vy = fmaf(f01.y, scl[c+1], shl[c+1]);
    float vz = fmaf(f23.x, scl[c+2], shl[c+2]);
    float vw = fmaf(f23.y, scl[c+3], shl[c+3]);
    int s = slot[ln];
    atomicAdd(&acc[s][c+0], vx);
    atomicAdd(&acc[s][c+1], vy);
    atomicAdd(&acc[s][c+2], vz);
    atomicAdd(&acc[s][c+3], vw);
    __syncthreads();

    int total = nsegS * 32;
    for (int i = tid; i < total; i += 256) {
        int r = i >> 5, dd = i & 31;
        float val = acc[r][dd];
        if (val != 0.f) atomicAdd(&pooled[(long)segg[r] * DIM + dd], val);
    }
}

// ---------------- final FC + ReLU ----------------
__global__ __launch_bounds__(256) void fc_kernel(
    const float* __restrict__ pooled, const float* __restrict__ Wfc,
    const float* __restrict__ bfc, float* __restrict__ out)
{
    __shared__ float Wl[DIM * OUTD];   // 16 KB
    for (int i = threadIdx.x; i < DIM * OUTD; i += 256) Wl[i] = Wfc[i];
    __syncthreads();
    int t = blockIdx.x * 256 + threadIdx.x;
    if (t >= N_GRAPHS * OUTD) return;
    int g = t >> 7;
    int o = t & (OUTD - 1);
    float acc = bfc[o];
    const float* pr = pooled + (long)g * DIM;
#pragma unroll
    for (int k = 0; k < DIM; ++k) acc += pr[k] * Wl[k * OUTD + o];
    out[t] = fmaxf(acc, 0.f);
}

extern "C" void kernel_launch(void* const* d_in, const int* in_sizes, int n_in,
                              void* d_out, int out_size, void* d_ws, size_t ws_size,
                              hipStream_t stream) {
    const float* x      = (const float*)d_in[0];
    const int*   ei     = (const int*)  d_in[1];
    const int*   batch  = (const int*)  d_in[2];
    const float* W1_0   = (const float*)d_in[3];
    const float* W1_rest= (const float*)d_in[4];
    const float* b1     = (const float*)d_in[5];
    const float* W2     = (const float*)d_in[6];
    const float* b2     = (const float*)d_in[7];
    const float* gamma  = (const float*)d_in[8];
    const float* beta   = (const float*)d_in[9];
    const float* Wfc    = (const float*)d_in[10];
    const float* bfc    = (const float*)d_in[11];
    float* out = (float*)d_out;

    int* wsi = (int*)d_ws;
    const size_t nf = (size_t)N_NODES * DIM;                   // 3.2M elems
    const size_t BD = (size_t)NBUK * STRIDE;                   // 1,801,728 ints
    int*   bdata  = wsi;
    unsigned short* zfpA = (unsigned short*)(wsi + BD);        // 6.4 MB
    unsigned short* zfpB = zfpA + nf;                          // 6.4 MB
    int*   edge_src = (int*)(zfpB + nf);                       // 1.6M ints
    int*   offs   = edge_src + N_EDGES;                        // 100,001
    int*   bcnt   = offs + (N_NODES + 1);                      // 391
    int*   bbase  = bcnt + NBUK;                               // 392
    float* pooled = (float*)(bbase + NBUK + 1);                // 65,536
    float* partial= pooled + (size_t)N_GRAPHS * DIM;           // 5*49*64
    float* ss     = partial + (size_t)NLAYERS * NSLOTS2 * 2 * DIM;
    float* W1p    = ss + NLAYERS * 2 * DIM;
    float* cvec   = W1p + NLAYERS * DIM * DIM;

    hipMemsetAsync(pooled, 0,
        ((size_t)N_GRAPHS * DIM + (size_t)NLAYERS * NSLOTS2 * 2 * DIM) *
        sizeof(float), stream);
    hipMemsetAsync(bcnt, 0, (size_t)NBUK * sizeof(int), stream);

    const int grpBlocks = (N_NODES * 8) / 256;                 // 3125

    // prep: bucket fill (391 blocks) || gemm1 (3125 blocks)
    prep_kernel<<<NBLK + grpBlocks, 256, 0, stream>>>(
        ei, bcnt, bdata, x, W1_0, zfpA);
    bscan_kernel<<<1, 512, 0, stream>>>(bcnt, bbase);
    cfill2_kernel<<<NBUK, 256, 0, stream>>>(bcnt, bbase, bdata, edge_src, offs);

    // layer 0: gather y0, no matmul fold
    layer_kernel<false><<<N_NODES / NPB, 256, 0, stream>>>(
        offs, edge_src, zfpA, nullptr, nullptr,
        b1, W2, b2, zfpB, partial);
    finalize_kernel<<<1, 256, 0, stream>>>(
        partial, gamma, beta, ss,
        W1_rest, W1p + DIM * DIM, cvec + DIM);

    // layers 1..4: fused affine+W1 fold
    const unsigned short* zi = zfpB;
    unsigned short* zo = zfpA;
    for (int i = 1; i < NLAYERS; ++i) {
        layer_kernel<true><<<N_NODES / NPB, 256, 0, stream>>>(
            offs, edge_src, zi,
            W1p + (size_t)i * DIM * DIM, cvec + (size_t)i * DIM,
            b1 + i * DIM, W2 + (size_t)i * DIM * DIM, b2 + i * DIM,
            zo, partial + (size_t)i * NSLOTS2 * 2 * DIM);
        const float* W1next = (i + 1 < NLAYERS) ? (W1_rest + (size_t)i * DIM * DIM)
                                                : nullptr;
        finalize_kernel<<<1, 256, 0, stream>>>(
            partial + (size_t)i * NSLOTS2 * 2 * DIM,
            gamma + i * DIM, beta + i * DIM, ss + i * 2 * DIM,
            W1next, W1p + (size_t)(i + 1) * DIM * DIM,
            cvec + (size_t)(i + 1) * DIM);
        const unsigned short* tmp = zi; zi = zo; zo = (unsigned short*)tmp;
    }

    // zi points at the final layer's output
    pool_kernel<<<N_NODES / 32, 256, 0, stream>>>(
        zi, batch, ss + (NLAYERS - 1) * 2 * DIM, pooled);
    fc_kernel<<<(N_GRAPHS * OUTD) / 256, 256, 0, stream>>>(pooled, Wfc, bfc, out);
}